// Round 1
// baseline (74.683 us; speedup 1.0000x reference)
//
#include <hip/hip_runtime.h>

#define NK 19
#define NB 8
#define NC 256
#define NP 8192           // 64*128
#define NBP (NB*NP)       // 65536
#define SSTR 39           // per-thread LDS bin stride (coprime with 32 banks)

// ---------------- kernel 1: argmax over classes + integer counts ----------------
__global__ __launch_bounds__(256) void k_argmax(const float* __restrict__ target,
                                                int* __restrict__ lab,
                                                int* __restrict__ counts) {
  __shared__ int lcnt[NK];
  if (threadIdx.x < NK) lcnt[threadIdx.x] = 0;
  __syncthreads();
  int g = blockIdx.x * 256 + threadIdx.x;              // pixel index in [0, NBP)
  const float* t = target + (size_t)g * NK;
  float best = t[0]; int bk = 0;
#pragma unroll
  for (int k = 1; k < NK; ++k) { float v = t[k]; if (v > best) { best = v; bk = k; } }
  lab[g] = bk;
  atomicAdd(&lcnt[bk], 1);
  __syncthreads();
  int b = g / NP;                                       // whole block shares b
  if (threadIdx.x < NK) atomicAdd(&counts[b * NK + threadIdx.x], lcnt[threadIdx.x]);
}

// ---------------- kernel 2: per-(b,c) class sums for S and T (deterministic) ----------------
__global__ __launch_bounds__(256) void k_sums(const float* __restrict__ fS,
                                              const float* __restrict__ fT,
                                              const int* __restrict__ lab,
                                              float* __restrict__ sums) {
  __shared__ float bins[256 * SSTR];                    // 39936 B
  int b = blockIdx.x >> 8;                              // / NC
  int c = blockIdx.x & 255;                             // % NC
  float* mine = &bins[threadIdx.x * SSTR];
#pragma unroll
  for (int j = 0; j < 38; ++j) mine[j] = 0.f;
  const float* rs = fS + ((size_t)b * NC + c) * NP;
  const float* rt = fT + ((size_t)b * NC + c) * NP;
  const int*   lb = lab + (size_t)b * NP;
#pragma unroll
  for (int i = 0; i < 8; ++i) {
    int p = i * 1024 + threadIdx.x * 4;
    float4 vs = *reinterpret_cast<const float4*>(rs + p);
    float4 vt = *reinterpret_cast<const float4*>(rt + p);
    int4   l  = *reinterpret_cast<const int4*>(lb + p);
    mine[l.x] += vs.x; mine[l.y] += vs.y; mine[l.z] += vs.z; mine[l.w] += vs.w;
    mine[NK + l.x] += vt.x; mine[NK + l.y] += vt.y; mine[NK + l.z] += vt.z; mine[NK + l.w] += vt.w;
  }
  for (int off = 128; off > 0; off >>= 1) {
    __syncthreads();
    if (threadIdx.x < off) {
      float* a = &bins[threadIdx.x * SSTR];
      const float* o = &bins[(threadIdx.x + off) * SSTR];
#pragma unroll
      for (int j = 0; j < 38; ++j) a[j] += o[j];
    }
  }
  __syncthreads();
  if (threadIdx.x < 38) {
    int f = threadIdx.x / NK, k = threadIdx.x - f * NK;
    sums[(((size_t)f * NB + b) * NC + c) * NK + k] = bins[threadIdx.x];
  }
}

// ---------------- kernel 3: means + per-(b,k) center norms ----------------
__global__ __launch_bounds__(256) void k_means(const float* __restrict__ sums,
                                               const int* __restrict__ counts,
                                               float* __restrict__ means,
                                               float* __restrict__ cnorm) {
  int b = blockIdx.x / NK, k = blockIdx.x % NK;
  int c = threadIdx.x;
  float cnt = (float)counts[b * NK + k] + 1e-6f;
  size_t iS = (((size_t)0 * NB + b) * NC + c) * NK + k;
  size_t iT = (((size_t)1 * NB + b) * NC + c) * NK + k;
  float mS = sums[iS] / cnt;
  float mT = sums[iT] / cnt;
  means[iS] = mS;
  means[iT] = mT;
  float sS = mS * mS, sT = mT * mT;
#pragma unroll
  for (int off = 32; off > 0; off >>= 1) { sS += __shfl_down(sS, off, 64); sT += __shfl_down(sT, off, 64); }
  __shared__ float redS[4], redT[4];
  int wid = threadIdx.x >> 6, lane = threadIdx.x & 63;
  if (lane == 0) { redS[wid] = sS; redT[wid] = sT; }
  __syncthreads();
  if (threadIdx.x == 0) {
    float tS = redS[0] + redS[1] + redS[2] + redS[3];
    float tT = redT[0] + redT[1] + redT[2] + redT[3];
    cnorm[b * NK + k]          = fmaxf(sqrtf(tS), 1e-8f);
    cnorm[NB * NK + b * NK + k] = fmaxf(sqrtf(tT), 1e-8f);
  }
}

// ---------------- kernel 4: per-pixel cosine + squared diff, block partials ----------------
__global__ __launch_bounds__(256) void k_cos(const float* __restrict__ fS,
                                             const float* __restrict__ fT,
                                             const int* __restrict__ lab,
                                             const float* __restrict__ means,
                                             const float* __restrict__ cnorm,
                                             float* __restrict__ partial) {
  __shared__ float mS[NC * NK];                         // 19456 B
  __shared__ float mT[NC * NK];                         // 19456 B
  int b  = blockIdx.x >> 5;                             // / 32 ptiles
  int pt = blockIdx.x & 31;
  const float* gmS = means + (size_t)b * NC * NK;
  const float* gmT = means + ((size_t)NB + b) * NC * NK;
  for (int i = threadIdx.x; i < NC * NK; i += 256) { mS[i] = gmS[i]; mT[i] = gmT[i]; }
  __syncthreads();
  int p = pt * 256 + threadIdx.x;
  int g = b * NP + p;
  int k = lab[g];
  const float* rs = fS + (size_t)b * NC * NP + p;
  const float* rt = fT + (size_t)b * NC * NP + p;
  float dS = 0.f, nS = 0.f, dT = 0.f, nT = 0.f;
#pragma unroll 8
  for (int c = 0; c < NC; ++c) {
    float vS = rs[(size_t)c * NP];
    float vT = rt[(size_t)c * NP];
    float cS = mS[c * NK + k];
    float cT = mT[c * NK + k];
    dS += vS * cS; nS += vS * vS;
    dT += vT * cT; nT += vT * vT;
  }
  float cnS = cnorm[b * NK + k];
  float cnT = cnorm[NB * NK + b * NK + k];
  float cosS = dS / (fmaxf(sqrtf(nS), 1e-8f) * cnS);
  float cosT = dT / (fmaxf(sqrtf(nT), 1e-8f) * cnT);
  float d = cosS - cosT;
  float v = d * d;
#pragma unroll
  for (int off = 32; off > 0; off >>= 1) v += __shfl_down(v, off, 64);
  __shared__ float red[4];
  int wid = threadIdx.x >> 6, lane = threadIdx.x & 63;
  if (lane == 0) red[wid] = v;
  __syncthreads();
  if (threadIdx.x == 0) partial[blockIdx.x] = red[0] + red[1] + red[2] + red[3];
}

// ---------------- kernel 5: final deterministic reduction ----------------
__global__ __launch_bounds__(256) void k_final(const float* __restrict__ partial,
                                               float* __restrict__ out) {
  float v = partial[threadIdx.x];
#pragma unroll
  for (int off = 32; off > 0; off >>= 1) v += __shfl_down(v, off, 64);
  __shared__ float red[4];
  int wid = threadIdx.x >> 6, lane = threadIdx.x & 63;
  if (lane == 0) red[wid] = v;
  __syncthreads();
  if (threadIdx.x == 0) out[0] = (red[0] + red[1] + red[2] + red[3]) * (1.0f / (float)NBP);
}

// ---------------- launch ----------------
extern "C" void kernel_launch(void* const* d_in, const int* in_sizes, int n_in,
                              void* d_out, int out_size, void* d_ws, size_t ws_size,
                              hipStream_t stream) {
  const float* fS     = (const float*)d_in[0];
  const float* fT     = (const float*)d_in[1];
  const float* target = (const float*)d_in[2];
  char* ws = (char*)d_ws;
  // ws layout (bytes): lab[NBP] ints | counts[NB*NK] ints | sums[2*NB*NC*NK] f32 |
  //                    means[2*NB*NC*NK] f32 | cnorm[2*NB*NK] f32 | partial[256] f32
  int*   lab     = (int*)  (ws + 0);        // 262144 B
  int*   counts  = (int*)  (ws + 262144);   // 608 B (pad to 1024)
  float* sums    = (float*)(ws + 263168);   // 311296 B
  float* means   = (float*)(ws + 574464);   // 311296 B
  float* cnorm   = (float*)(ws + 885760);   // 1216 B (pad to 2048)
  float* partial = (float*)(ws + 887808);   // 1024 B
  float* out = (float*)d_out;

  hipMemsetAsync(counts, 0, NB * NK * sizeof(int), stream);
  k_argmax<<<NBP / 256, 256, 0, stream>>>(target, lab, counts);
  k_sums  <<<NB * NC,   256, 0, stream>>>(fS, fT, lab, sums);
  k_means <<<NB * NK,   256, 0, stream>>>(sums, counts, means, cnorm);
  k_cos   <<<NB * (NP / 256), 256, 0, stream>>>(fS, fT, lab, means, cnorm, partial);
  k_final <<<1, 256, 0, stream>>>(partial, out);
}

// Round 2
// 64.301 us; speedup vs baseline: 1.1615x; 1.1615x over previous
//
#include <hip/hip_runtime.h>

#define NK 19
#define NB 8
#define NC 256
#define NP 8192           // 64*128
#define NBP (NB*NP)       // 65536
#define HS 21             // hist stride (gcd(21,32)=1 -> bank spread)

typedef unsigned char u8;

// ---------------- kernel 1: argmax over classes + integer counts ----------------
__global__ __launch_bounds__(256) void k_argmax(const float* __restrict__ target,
                                                u8* __restrict__ lab,
                                                int* __restrict__ counts) {
  __shared__ float tl[256 * NK];                 // 19456 B
  __shared__ int lcnt[NK];
  if (threadIdx.x < NK) lcnt[threadIdx.x] = 0;
  // coalesced stage: 1216 float4s
  const float4* src = (const float4*)(target + (size_t)blockIdx.x * (256 * NK));
  float4* dst = (float4*)tl;
  for (int i = threadIdx.x; i < 256 * NK / 4; i += 256) dst[i] = src[i];
  __syncthreads();
  const float* row = &tl[threadIdx.x * NK];
  float best = row[0]; int bk = 0;
#pragma unroll
  for (int k = 1; k < NK; ++k) { float v = row[k]; if (v > best) { best = v; bk = k; } }
  int g = blockIdx.x * 256 + threadIdx.x;
  lab[g] = (u8)bk;
  atomicAdd(&lcnt[bk], 1);
  __syncthreads();
  int b = g >> 13;                               // / NP (block is within one b)
  if (threadIdx.x < NK) atomicAdd(&counts[b * NK + threadIdx.x], lcnt[threadIdx.x]);
}

// ---------------- kernel 2: per-(feat,b,c) class sums (deterministic) ----------------
__global__ __launch_bounds__(256) void k_sums(const float* __restrict__ fS,
                                              const float* __restrict__ fT,
                                              const u8* __restrict__ lab,
                                              float* __restrict__ sums) {
  __shared__ float bins[256 * HS];               // 21504 B
  __shared__ float pbuf[152];
  int id = blockIdx.x;                           // [0, 2*NB*NC)
  int f = id >> 11;
  int b = (id >> 8) & 7;
  int c = id & 255;
  const float* row = (f ? fT : fS) + ((size_t)(b * NC + c)) * NP;
  const uchar4* lb = (const uchar4*)(lab + b * NP);
  float* mine = &bins[threadIdx.x * HS];
#pragma unroll
  for (int j = 0; j < NK; ++j) mine[j] = 0.f;
  const float4* rv = (const float4*)row;
#pragma unroll
  for (int i = 0; i < 8; ++i) {
    int p4 = i * 256 + threadIdx.x;
    float4 v = rv[p4];
    uchar4 l = lb[p4];
    mine[l.x] += v.x; mine[l.y] += v.y; mine[l.z] += v.z; mine[l.w] += v.w;
  }
  __syncthreads();
  int t = threadIdx.x;
  // transpose reduce: 19 bins x 256 rows; thread (k,s) sums rows s+8j
  if (t < 152) {
    int k = t >> 3, s = t & 7;
    float acc = 0.f;
#pragma unroll
    for (int j = 0; j < 32; ++j) acc += bins[(s + 8 * j) * HS + k];
    pbuf[t] = acc;
  }
  __syncthreads();
  if (t < NK) {
    float tot = 0.f;
#pragma unroll
    for (int s = 0; s < 8; ++s) tot += pbuf[t * 8 + s];
    sums[(size_t)id * NK + t] = tot;             // [(f*NB+b)*NC+c]*NK + k
  }
}

// ---------------- kernel 3: means + per-(f,b,k) center norms ----------------
__global__ __launch_bounds__(256) void k_means(const float* __restrict__ sums,
                                               const int* __restrict__ counts,
                                               float* __restrict__ means,
                                               float* __restrict__ cnorm) {
  int b = blockIdx.x / NK, k = blockIdx.x % NK;
  int c = threadIdx.x;
  float cnt = (float)counts[b * NK + k] + 1e-6f;
  size_t iS = ((size_t)(b * NC + c)) * NK + k;
  size_t iT = ((size_t)((NB + b) * NC + c)) * NK + k;
  float mS = sums[iS] / cnt;
  float mT = sums[iT] / cnt;
  means[iS] = mS;
  means[iT] = mT;
  float sS = mS * mS, sT = mT * mT;
#pragma unroll
  for (int off = 32; off > 0; off >>= 1) { sS += __shfl_down(sS, off, 64); sT += __shfl_down(sT, off, 64); }
  __shared__ float redS[4], redT[4];
  int wid = threadIdx.x >> 6, lane = threadIdx.x & 63;
  if (lane == 0) { redS[wid] = sS; redT[wid] = sT; }
  __syncthreads();
  if (threadIdx.x == 0) {
    float tS = redS[0] + redS[1] + redS[2] + redS[3];
    float tT = redT[0] + redT[1] + redT[2] + redT[3];
    cnorm[b * NK + k]           = fmaxf(sqrtf(tS), 1e-8f);
    cnorm[NB * NK + b * NK + k] = fmaxf(sqrtf(tT), 1e-8f);
  }
}

// ---------------- kernel 4: per-pixel cosine + squared diff (4-way channel split) ----------------
__global__ __launch_bounds__(256) void k_cos(const float* __restrict__ fS,
                                             const float* __restrict__ fT,
                                             const u8* __restrict__ lab,
                                             const float* __restrict__ means,
                                             const float* __restrict__ cnorm,
                                             float* __restrict__ partial) {
  __shared__ float R[1024];                      // 4 KB
  int b = blockIdx.x >> 7, pt = blockIdx.x & 127;
  int t = threadIdx.x;
  int px = t & 63, cg = t >> 6;                  // 4 channel-groups x 64 pixels
  int p = pt * 64 + px;
  int k = lab[b * NP + p];
  const float* rs = fS + (size_t)b * NC * NP + p;
  const float* rt = fT + (size_t)b * NC * NP + p;
  const float* mSb = means + (size_t)(b * NC) * NK;
  const float* mTb = means + (size_t)((NB + b) * NC) * NK;
  float dS = 0.f, nS = 0.f, dT = 0.f, nT = 0.f;
  int c0 = cg * 64;
#pragma unroll 8
  for (int j = 0; j < 64; ++j) {
    int c = c0 + j;
    float vS = rs[(size_t)c * NP];
    float vT = rt[(size_t)c * NP];
    float cS = mSb[c * NK + k];                  // L1-resident gather (<=2 lines/wave)
    float cT = mTb[c * NK + k];
    dS += vS * cS; nS += vS * vS;
    dT += vT * cT; nT += vT * vT;
  }
  R[t] = dS; R[256 + t] = nS; R[512 + t] = dT; R[768 + t] = nT;
  __syncthreads();
  if (t < 64) {                                  // conflict-free stride-1 reads
    dS = R[t]       + R[64 + t]  + R[128 + t] + R[192 + t];
    nS = R[256 + t] + R[320 + t] + R[384 + t] + R[448 + t];
    dT = R[512 + t] + R[576 + t] + R[640 + t] + R[704 + t];
    nT = R[768 + t] + R[832 + t] + R[896 + t] + R[960 + t];
    float cnS = cnorm[b * NK + k];
    float cnT = cnorm[NB * NK + b * NK + k];
    float cosS = dS / (fmaxf(sqrtf(nS), 1e-8f) * cnS);
    float cosT = dT / (fmaxf(sqrtf(nT), 1e-8f) * cnT);
    float d = cosS - cosT;
    float v = d * d;
#pragma unroll
    for (int off = 32; off > 0; off >>= 1) v += __shfl_down(v, off, 64);
    if (px == 0) partial[blockIdx.x] = v;
  }
}

// ---------------- kernel 5: final deterministic reduction (1024 partials) ----------------
__global__ __launch_bounds__(256) void k_final(const float* __restrict__ partial,
                                               float* __restrict__ out) {
  int t = threadIdx.x;
  float v = partial[t] + partial[256 + t] + partial[512 + t] + partial[768 + t];
#pragma unroll
  for (int off = 32; off > 0; off >>= 1) v += __shfl_down(v, off, 64);
  __shared__ float red[4];
  int wid = t >> 6, lane = t & 63;
  if (lane == 0) red[wid] = v;
  __syncthreads();
  if (t == 0) out[0] = (red[0] + red[1] + red[2] + red[3]) * (1.0f / (float)NBP);
}

// ---------------- launch ----------------
extern "C" void kernel_launch(void* const* d_in, const int* in_sizes, int n_in,
                              void* d_out, int out_size, void* d_ws, size_t ws_size,
                              hipStream_t stream) {
  const float* fS     = (const float*)d_in[0];
  const float* fT     = (const float*)d_in[1];
  const float* target = (const float*)d_in[2];
  char* ws = (char*)d_ws;
  // ws layout: lab u8[65536] | counts int[152] | sums f32[2*8*256*19] |
  //            means f32[2*8*256*19] | cnorm f32[2*8*19] | partial f32[1024]
  u8*    lab     = (u8*)   (ws + 0);        // 65536 B
  int*   counts  = (int*)  (ws + 65536);    // 608 B (pad to 66560)
  float* sums    = (float*)(ws + 66560);    // 311296 B -> 377856
  float* means   = (float*)(ws + 377856);   // 311296 B -> 689152
  float* cnorm   = (float*)(ws + 689152);   // 1216 B (pad to 690432)
  float* partial = (float*)(ws + 690432);   // 4096 B
  float* out = (float*)d_out;

  hipMemsetAsync(counts, 0, NB * NK * sizeof(int), stream);
  k_argmax<<<NBP / 256,   256, 0, stream>>>(target, lab, counts);
  k_sums  <<<2 * NB * NC, 256, 0, stream>>>(fS, fT, lab, sums);
  k_means <<<NB * NK,     256, 0, stream>>>(sums, counts, means, cnorm);
  k_cos   <<<NB * (NP / 64), 256, 0, stream>>>(fS, fT, lab, means, cnorm, partial);
  k_final <<<1, 256, 0, stream>>>(partial, out);
}